// Round 2
// baseline (3387.967 us; speedup 1.0000x reference)
//
#include <hip/hip_runtime.h>
#include <stdint.h>
#include <stddef.h>

// SpatialNSA on MI355X — round 2: f32 in/out (reference dtypes), f32 math.
// Correctness-first full pipeline. No atomics -> deterministic.

#define DEV __device__ __forceinline__

// ---------------- transpose: x (B,C,N) f32 -> xs (B,N,C) f32 -------------
__global__ void k_xs(const float* __restrict__ x, float* __restrict__ xs){
    __shared__ float t[32][33];
    int b = blockIdx.z; int c0 = blockIdx.y*32; int n0 = blockIdx.x*32;
    int tx = threadIdx.x, ty = threadIdx.y;            // (32,8)
    for(int i=ty;i<32;i+=8)
        t[i][tx] = x[((size_t)(b*256 + c0+i))*4096 + n0 + tx];
    __syncthreads();
    for(int i=ty;i<32;i+=8)
        xs[((size_t)(b*4096 + n0+i))*256 + c0 + tx] = t[tx][i];
}

// ---------------- generic GEMM: C(M,N) = act(A(M,K) @ W(K,N) + bias) ----------
// A f32 row-major, W/bias f32, C f32. act: 0 none, 1 gelu(exact), 2 sigmoid.
__global__ __launch_bounds__(256) void k_gemm(
        const float* __restrict__ A, const float* __restrict__ W,
        const float* __restrict__ bias, float* __restrict__ C,
        int M, int K, int Nn, int act)
{
    __shared__ float As[16][68];
    __shared__ float Bs[16][64];
    const int m0 = blockIdx.y*64, n0 = blockIdx.x*64;
    const int t = threadIdx.x, tx = t&15, ty = t>>4;
    float acc[4][4] = {};
    const int am = t>>2;           // 0..63
    const int ak = (t&3)*4;        // 0,4,8,12
    const bool arow_ok = (m0+am) < M;

    for(int k0=0;k0<K;k0+=16){
        float4 av = make_float4(0.f,0.f,0.f,0.f);
        if(arow_ok) av = *reinterpret_cast<const float4*>(&A[(size_t)(m0+am)*K + k0 + ak]);
        As[ak+0][am]=av.x; As[ak+1][am]=av.y; As[ak+2][am]=av.z; As[ak+3][am]=av.w;
        if((Nn & 3) == 0){
            int bn = (t&15)*4, bk = t>>4;
            float4 bv = make_float4(0.f,0.f,0.f,0.f);
            if(n0+bn < Nn)
                bv = *reinterpret_cast<const float4*>(&W[(size_t)(k0+bk)*Nn + n0+bn]);
            Bs[bk][bn]=bv.x; Bs[bk][bn+1]=bv.y; Bs[bk][bn+2]=bv.z; Bs[bk][bn+3]=bv.w;
        } else {
            int n = t&63, kb = t>>6;
            #pragma unroll
            for(int r=0;r<4;r++){
                int kk = r*4 + kb; float v = 0.f;
                if(n0+n < Nn) v = W[(size_t)(k0+kk)*Nn + n0+n];
                Bs[kk][n] = v;
            }
        }
        __syncthreads();
        #pragma unroll
        for(int kk=0;kk<16;kk++){
            float a0=As[kk][ty*4+0], a1=As[kk][ty*4+1], a2=As[kk][ty*4+2], a3=As[kk][ty*4+3];
            float b0=Bs[kk][tx*4+0], b1=Bs[kk][tx*4+1], b2=Bs[kk][tx*4+2], b3=Bs[kk][tx*4+3];
            acc[0][0]=fmaf(a0,b0,acc[0][0]); acc[0][1]=fmaf(a0,b1,acc[0][1]);
            acc[0][2]=fmaf(a0,b2,acc[0][2]); acc[0][3]=fmaf(a0,b3,acc[0][3]);
            acc[1][0]=fmaf(a1,b0,acc[1][0]); acc[1][1]=fmaf(a1,b1,acc[1][1]);
            acc[1][2]=fmaf(a1,b2,acc[1][2]); acc[1][3]=fmaf(a1,b3,acc[1][3]);
            acc[2][0]=fmaf(a2,b0,acc[2][0]); acc[2][1]=fmaf(a2,b1,acc[2][1]);
            acc[2][2]=fmaf(a2,b2,acc[2][2]); acc[2][3]=fmaf(a2,b3,acc[2][3]);
            acc[3][0]=fmaf(a3,b0,acc[3][0]); acc[3][1]=fmaf(a3,b1,acc[3][1]);
            acc[3][2]=fmaf(a3,b2,acc[3][2]); acc[3][3]=fmaf(a3,b3,acc[3][3]);
        }
        __syncthreads();
    }
    #pragma unroll
    for(int i=0;i<4;i++){
        int m = m0 + ty*4 + i;
        if(m >= M) continue;
        #pragma unroll
        for(int j=0;j<4;j++){
            int n = n0 + tx*4 + j;
            if(n >= Nn) continue;
            float v = acc[i][j] + bias[n];
            if(act==1)      v = 0.5f*v*(1.0f + erff(v*0.70710678118654752f));
            else if(act==2) v = 1.0f/(1.0f + expf(-v));
            C[(size_t)m*Nn + n] = v;
        }
    }
}

// ------------- unfold (CBS=4, stride 2) with torch-quirk flat order -----------
// out[(b*961+blk)][j] = qkv[b, y*64+x, chanBase + (j>>4)] (+ pos[j])
__global__ void k_unfold(const float* __restrict__ qkv, const float* __restrict__ pos,
                         float* __restrict__ outA, int chanBase){
    int row = blockIdx.x;                 // 0..3843
    int b = row / 961, blk = row % 961;
    int bi = blk / 31, bj = blk % 31;
    for(int j = threadIdx.x; j < 4096; j += 256){
        int ch = j >> 4;
        int kh = (j >> 2) & 3, kw = j & 3;
        int n = (bi*2 + kh)*64 + (bj*2 + kw);
        float v = qkv[((size_t)(b*4096) + n)*768 + chanBase + ch];
        if(pos) v += pos[j];
        outA[(size_t)row*4096 + j] = v;
    }
}

// ------------- compressed attention: 961 keys, fused 2-pass + importance ------
__global__ __launch_bounds__(64) void k_attn_cmp(
    const float* __restrict__ qkv, const float* __restrict__ kc, const float* __restrict__ vc,
    float* __restrict__ outp, float* __restrict__ impp)
{
    const int qt = blockIdx.x, h = blockIdx.y, b = blockIdx.z;
    const int lane = threadIdx.x;
    const int q = qt*64 + lane;
    const float* qptr = &qkv[((size_t)(b*4096 + q))*768 + h*64];
    float qreg[64];
    #pragma unroll
    for(int d=0; d<64; ++d) qreg[d] = qptr[d];

    __shared__ float lk[32][64];
    __shared__ float lv[32][64];

    float m = -1e30f, l = 0.f;
    for(int base=0; base<961; base+=32){
        int nb = 961 - base; if(nb > 32) nb = 32;
        __syncthreads();
        for(int r=0; r<nb; ++r)
            lk[r][lane] = kc[((size_t)(b*961 + base + r))*256 + h*64 + lane];
        __syncthreads();
        for(int r=0; r<nb; ++r){
            float s0=0,s1=0,s2=0,s3=0;
            #pragma unroll
            for(int d=0; d<64; d+=4){
                s0 = fmaf(qreg[d+0], lk[r][d+0], s0);
                s1 = fmaf(qreg[d+1], lk[r][d+1], s1);
                s2 = fmaf(qreg[d+2], lk[r][d+2], s2);
                s3 = fmaf(qreg[d+3], lk[r][d+3], s3);
            }
            float s = ((s0+s1)+(s2+s3)) * 0.125f;
            float mn = fmaxf(m, s);
            l = l*__expf(m - mn) + __expf(s - mn);
            m = mn;
        }
    }
    const float inv_l = 1.f / l;

    float acc[64];
    #pragma unroll
    for(int d=0; d<64; ++d) acc[d] = 0.f;
    const int wgrow = (b*4 + h)*64 + qt;
    for(int base=0; base<961; base+=32){
        int nb = 961 - base; if(nb > 32) nb = 32;
        __syncthreads();
        for(int r=0; r<nb; ++r){
            lk[r][lane] = kc[((size_t)(b*961 + base + r))*256 + h*64 + lane];
            lv[r][lane] = vc[((size_t)(b*961 + base + r))*256 + h*64 + lane];
        }
        __syncthreads();
        for(int r=0; r<nb; ++r){
            float s0=0,s1=0,s2=0,s3=0;
            #pragma unroll
            for(int d=0; d<64; d+=4){
                s0 = fmaf(qreg[d+0], lk[r][d+0], s0);
                s1 = fmaf(qreg[d+1], lk[r][d+1], s1);
                s2 = fmaf(qreg[d+2], lk[r][d+2], s2);
                s3 = fmaf(qreg[d+3], lk[r][d+3], s3);
            }
            float p = __expf(((s0+s1)+(s2+s3))*0.125f - m);
            #pragma unroll
            for(int d=0; d<64; ++d) acc[d] = fmaf(p, lv[r][d], acc[d]);
            float pn = p * inv_l;
            #pragma unroll
            for(int off=32; off>0; off>>=1) pn += __shfl_xor(pn, off);
            if(lane==0) impp[(size_t)wgrow*961 + base + r] = pn;
        }
    }
    float* op = &outp[((size_t)(b*4096 + q))*256 + h*64];
    #pragma unroll
    for(int d=0; d<64; ++d) op[d] = acc[d]*inv_l;
}

// ------------- deterministic importance reduce ------------
__global__ void k_imp_reduce(const float* __restrict__ impp, float* __restrict__ imp){
    int blk = blockIdx.x*256 + threadIdx.x;
    int b = blockIdx.y;
    if(blk >= 961) return;
    float s = 0.f;
    for(int r=0;r<256;r++) s += impp[(size_t)(b*256 + r)*961 + blk];
    imp[b*961 + blk] = s;
}

// ------------- top-16 with lowest-index tie-break ----------------------------
__global__ void k_topk(const float* __restrict__ imp, int* __restrict__ idx){
    int b = blockIdx.x;
    __shared__ float v[961];
    __shared__ float bestv[256];
    __shared__ int   besti[256];
    int t = threadIdx.x;
    for(int i=t;i<961;i+=256) v[i] = imp[b*961+i];
    __syncthreads();
    for(int it=0; it<16; it++){
        float bv = -1e30f; int bi = 0;
        for(int i=t;i<961;i+=256){
            if(v[i] > bv){ bv=v[i]; bi=i; }
        }
        bestv[t]=bv; besti[t]=bi;
        __syncthreads();
        if(t==0){
            float gb=-1e30f; int gi=0;
            for(int i=0;i<256;i++){
                if(bestv[i]>gb || (bestv[i]==gb && besti[i]<gi)){ gb=bestv[i]; gi=besti[i]; }
            }
            idx[b*16+it] = gi;
            v[gi] = -1e30f;
        }
        __syncthreads();
    }
}

// ------------- gather selected K/V with quirk layout + clip to 255 ------------
__global__ void k_gather_sel(const float* __restrict__ qkv2, const int* __restrict__ idx,
                             float* __restrict__ Ks, float* __restrict__ Vs){
    int row = blockIdx.x;            // b*256 + t ; t = sel*16 + p
    int b = row >> 8, tt = row & 255;
    int sel = tt >> 4, p = tt & 15;
    int blk = idx[b*16+sel]; if(blk > 255) blk = 255;
    int bi = blk >> 4, bj = blk & 15;
    int cc = threadIdx.x;
    int y = bi*4 + ((cc>>2)&3), xx = bj*4 + (cc&3);
    int ch = p*16 + (cc>>4);
    size_t src = ((size_t)(b*4096) + y*64 + xx)*768;
    Ks[(size_t)row*256 + cc] = qkv2[src + 256 + ch];
    Vs[(size_t)row*256 + cc] = qkv2[src + 512 + ch];
}

// ------------- selected attention: 256 keys ----------------------------------
__global__ __launch_bounds__(64) void k_attn_slc(
    const float* __restrict__ qkv2, const float* __restrict__ Ks, const float* __restrict__ Vs,
    float* __restrict__ outp)
{
    const int qt = blockIdx.x, h = blockIdx.y, b = blockIdx.z;
    const int lane = threadIdx.x;
    const int q = qt*64 + lane;
    const float* qptr = &qkv2[((size_t)(b*4096 + q))*768 + h*64];
    float qreg[64];
    #pragma unroll
    for(int d=0; d<64; ++d) qreg[d] = qptr[d];
    __shared__ float lk[32][64];
    __shared__ float lv[32][64];
    float m = -1e30f, l = 0.f;
    for(int base=0; base<256; base+=32){
        __syncthreads();
        for(int r=0; r<32; ++r)
            lk[r][lane] = Ks[((size_t)(b*256 + base + r))*256 + h*64 + lane];
        __syncthreads();
        for(int r=0; r<32; ++r){
            float s0=0,s1=0,s2=0,s3=0;
            #pragma unroll
            for(int d=0; d<64; d+=4){
                s0 = fmaf(qreg[d+0], lk[r][d+0], s0);
                s1 = fmaf(qreg[d+1], lk[r][d+1], s1);
                s2 = fmaf(qreg[d+2], lk[r][d+2], s2);
                s3 = fmaf(qreg[d+3], lk[r][d+3], s3);
            }
            float s = ((s0+s1)+(s2+s3)) * 0.125f;
            float mn = fmaxf(m, s);
            l = l*__expf(m - mn) + __expf(s - mn);
            m = mn;
        }
    }
    const float inv_l = 1.f / l;
    float acc[64];
    #pragma unroll
    for(int d=0; d<64; ++d) acc[d] = 0.f;
    for(int base=0; base<256; base+=32){
        __syncthreads();
        for(int r=0; r<32; ++r){
            lk[r][lane] = Ks[((size_t)(b*256 + base + r))*256 + h*64 + lane];
            lv[r][lane] = Vs[((size_t)(b*256 + base + r))*256 + h*64 + lane];
        }
        __syncthreads();
        for(int r=0; r<32; ++r){
            float s0=0,s1=0,s2=0,s3=0;
            #pragma unroll
            for(int d=0; d<64; d+=4){
                s0 = fmaf(qreg[d+0], lk[r][d+0], s0);
                s1 = fmaf(qreg[d+1], lk[r][d+1], s1);
                s2 = fmaf(qreg[d+2], lk[r][d+2], s2);
                s3 = fmaf(qreg[d+3], lk[r][d+3], s3);
            }
            float p = __expf(((s0+s1)+(s2+s3))*0.125f - m);
            #pragma unroll
            for(int d=0; d<64; ++d) acc[d] = fmaf(p, lv[r][d], acc[d]);
        }
    }
    float* op = &outp[((size_t)(b*4096 + q))*256 + h*64];
    #pragma unroll
    for(int d=0; d<64; ++d) op[d] = acc[d]*inv_l;
}

// ------------- build padded window tokens xw (400*49, 256) -------------------
__global__ void k_xw(const float* __restrict__ xs, float* __restrict__ xw){
    int row = blockIdx.x;             // wb*49 + t
    int wb = row / 49, t = row % 49;
    int b = wb / 100, wrem = wb % 100;
    int wy = wrem / 10, wx = wrem % 10;
    int ty = t / 7, tx = t % 7;
    int y = wy*7 + ty, xx = wx*7 + tx;
    int c = threadIdx.x;
    float v = 0.f;
    if(y < 64 && xx < 64) v = xs[((size_t)(b*4096) + y*64 + xx)*256 + c];
    xw[(size_t)row*256 + c] = v;
}

// ------------- window attention: 49 tokens, rel-pos bias ---------------------
__global__ __launch_bounds__(64) void k_attn_win(
    const float* __restrict__ qkvw, const float* __restrict__ btab,
    float* __restrict__ outp)
{
    const int wb = blockIdx.x, h = blockIdx.y;
    const int lane = threadIdx.x;
    __shared__ float lk[49][64];
    __shared__ float lv[49][64];
    __shared__ float ls[49][51];
    __shared__ float lbias[169];
    for(int i=lane;i<169;i+=64) lbias[i] = btab[i*4 + h];
    for(int r=0;r<49;r++){
        lk[r][lane] = qkvw[((size_t)(wb*49 + r))*768 + 256 + h*64 + lane];
        lv[r][lane] = qkvw[((size_t)(wb*49 + r))*768 + 512 + h*64 + lane];
    }
    __syncthreads();
    if(lane < 49){
        const float* qptr = &qkvw[((size_t)(wb*49 + lane))*768 + h*64];
        float qreg[64];
        #pragma unroll
        for(int d=0;d<64;++d) qreg[d] = qptr[d];
        int ih = lane/7, iw = lane%7;
        float m = -1e30f;
        for(int j=0;j<49;j++){
            float s0=0,s1=0,s2=0,s3=0;
            #pragma unroll
            for(int d=0; d<64; d+=4){
                s0 = fmaf(qreg[d+0], lk[j][d+0], s0);
                s1 = fmaf(qreg[d+1], lk[j][d+1], s1);
                s2 = fmaf(qreg[d+2], lk[j][d+2], s2);
                s3 = fmaf(qreg[d+3], lk[j][d+3], s3);
            }
            int jh=j/7, jw=j%7;
            float s = ((s0+s1)+(s2+s3))*0.125f + lbias[(ih-jh+6)*13 + (iw-jw+6)];
            ls[lane][j] = s;
            m = fmaxf(m, s);
        }
        float l = 0.f;
        for(int j=0;j<49;j++){ float p = __expf(ls[lane][j] - m); ls[lane][j] = p; l += p; }
        float inv = 1.f/l;
        float* op = &outp[((size_t)(wb*49 + lane))*256 + h*64];
        for(int d=0;d<64;d++){
            float a0=0,a1=0;
            for(int j=0;j<48;j+=2){
                a0 = fmaf(ls[lane][j],   lv[j][d],   a0);
                a1 = fmaf(ls[lane][j+1], lv[j+1][d], a1);
            }
            a0 = fmaf(ls[lane][48], lv[48][d], a0);
            op[d] = (a0+a1)*inv;
        }
    }
}

// ------------- final gated combine + transpose to (B,C,H,W) f32 -------------
__global__ void k_combine(const float* __restrict__ ocp, const float* __restrict__ osp,
                          const float* __restrict__ owp, const float* __restrict__ g,
                          float* __restrict__ out){
    __shared__ float tile[32][33];
    int b = blockIdx.z; int c0 = blockIdx.y*32, n0 = blockIdx.x*32;
    int tx = threadIdx.x, ty = threadIdx.y;    // (32,8)
    for(int i=ty;i<32;i+=8){
        int n = n0 + i;
        float g0 = g[(size_t)(b*4096+n)*3 + 0];
        float g1 = g[(size_t)(b*4096+n)*3 + 1];
        float g2 = g[(size_t)(b*4096+n)*3 + 2];
        int y = n >> 6, xx = n & 63;
        int wy = y/7, ty2 = y%7, wx = xx/7, tx2 = xx%7;
        size_t wrow = (size_t)(b*100 + wy*10 + wx)*49 + ty2*7 + tx2;
        size_t base = ((size_t)(b*4096) + n)*256 + c0;
        float vc = ocp[base + tx];
        float vs = osp[base + tx];
        float vw = owp[wrow*256 + c0 + tx];
        tile[i][tx] = g0*vc + g1*vs + g2*vw;
    }
    __syncthreads();
    for(int i=ty;i<32;i+=8)
        out[((size_t)(b*256 + c0+i))*4096 + n0 + tx] = tile[tx][i];
}

// =============================== host side ===================================
extern "C" void kernel_launch(void* const* d_in, const int* in_sizes, int n_in,
                              void* d_out, int out_size, void* d_ws, size_t ws_size,
                              hipStream_t stream)
{
    typedef const float* fp;
    fp x          = (fp)d_in[0];
    fp qkv_cmp_w  = (fp)d_in[1];  fp qkv_cmp_b = (fp)d_in[2];
    fp qkv_slc_w  = (fp)d_in[3];  fp qkv_slc_b = (fp)d_in[4];
    fp cmpk_w1    = (fp)d_in[5];  fp cmpk_b1   = (fp)d_in[6];
    fp cmpk_w2    = (fp)d_in[7];  fp cmpk_b2   = (fp)d_in[8];
    fp cmpv_w1    = (fp)d_in[9];  fp cmpv_b1   = (fp)d_in[10];
    fp cmpv_w2    = (fp)d_in[11]; fp cmpv_b2   = (fp)d_in[12];
    fp pos_embed  = (fp)d_in[13];
    fp win_qkv_w  = (fp)d_in[14]; fp win_qkv_b = (fp)d_in[15];
    fp win_proj_w = (fp)d_in[16]; fp win_proj_b= (fp)d_in[17];
    fp win_btab   = (fp)d_in[18];
    fp proj_cmp_w = (fp)d_in[19]; fp proj_cmp_b= (fp)d_in[20];
    fp proj_slc_w = (fp)d_in[21]; fp proj_slc_b= (fp)d_in[22];
    fp gate_w1    = (fp)d_in[23]; fp gate_b1   = (fp)d_in[24];
    fp gate_w2    = (fp)d_in[25]; fp gate_b2   = (fp)d_in[26];
    (void)in_sizes; (void)n_in; (void)out_size;

    char* ws = (char*)d_ws;
    size_t off = 0;
    auto alloc = [&](size_t bytes)->size_t{
        size_t r = off; off += (bytes + 255) & ~(size_t)255; return r;
    };
    const size_t XS   = alloc((size_t)16384*256*4);   // xs (B*N, C)
    const size_t QKV  = alloc((size_t)16384*768*4);   // qkv_cmp, then qkv_slc
    const size_t BIGA = alloc((size_t)3844*4096*4);   // fk / fv / qkv_win
    const size_t HID  = alloc((size_t)3844*512*4);    // mlp hidden / gate hidden
    const size_t KC   = alloc((size_t)3844*256*4);
    const size_t VC   = alloc((size_t)3844*256*4);
    const size_t OC   = alloc((size_t)16384*256*4);   // out_cmp_pre, then out_slc_pre
    const size_t IMPP = alloc((size_t)1024*961*4);
    const size_t IMP  = alloc((size_t)4*961*4);
    const size_t IDX  = alloc((size_t)4*16*4);
    const size_t OCP  = alloc((size_t)16384*256*4);   // out_cmp (post-proj)
    const size_t XW   = alloc((size_t)19600*256*4);   // xw -> owin_tok -> out_slc(post)
    const size_t OWP  = alloc((size_t)19600*256*4);   // out_win (post-proj, token layout)
    const size_t KS   = alloc((size_t)4*256*256*4);
    const size_t VS   = alloc((size_t)4*256*256*4);
    const size_t G2   = alloc((size_t)16384*3*4);
    if(off > ws_size) return;   // fail loudly if ws too small

    float* p_xs  = (float*)(ws + XS);
    float* p_qkv = (float*)(ws + QKV);
    float* p_big = (float*)(ws + BIGA);
    float* p_hid = (float*)(ws + HID);
    float* p_kc  = (float*)(ws + KC);
    float* p_vc  = (float*)(ws + VC);
    float* p_oc  = (float*)(ws + OC);
    float* p_impp= (float*)(ws + IMPP);
    float* p_imp = (float*)(ws + IMP);
    int*   p_idx = (int*)  (ws + IDX);
    float* p_ocp = (float*)(ws + OCP);
    float* p_xw  = (float*)(ws + XW);
    float* p_owp = (float*)(ws + OWP);
    float* p_ks  = (float*)(ws + KS);
    float* p_vs  = (float*)(ws + VS);
    float* p_g   = (float*)(ws + G2);

    auto gemm = [&](const float* A, fp W, fp bias, float* Cc, int M, int K, int Nn, int act){
        dim3 g((Nn+63)/64, (M+63)/64);
        k_gemm<<<g, 256, 0, stream>>>(A, W, bias, Cc, M, K, Nn, act);
    };

    // 1. xs = transpose(x)
    k_xs<<<dim3(128,8,4), dim3(32,8), 0, stream>>>(x, p_xs);
    // 2. qkv_cmp
    gemm(p_xs, qkv_cmp_w, qkv_cmp_b, p_qkv, 16384, 256, 768, 0);
    // 3-5. compressed K path: unfold(+pos) -> mlp1(gelu) -> mlp2
    k_unfold<<<3844, 256, 0, stream>>>(p_qkv, pos_embed, p_big, 256);
    gemm(p_big, cmpk_w1, cmpk_b1, p_hid, 3844, 4096, 512, 1);
    gemm(p_hid, cmpk_w2, cmpk_b2, p_kc, 3844, 512, 256, 0);
    // 6-8. compressed V path
    k_unfold<<<3844, 256, 0, stream>>>(p_qkv, nullptr, p_big, 512);
    gemm(p_big, cmpv_w1, cmpv_b1, p_hid, 3844, 4096, 512, 1);
    gemm(p_hid, cmpv_w2, cmpv_b2, p_vc, 3844, 512, 256, 0);
    // 9. compressed attention + importance partials
    k_attn_cmp<<<dim3(64,4,4), 64, 0, stream>>>(p_qkv, p_kc, p_vc, p_oc, p_impp);
    k_imp_reduce<<<dim3(4,4), 256, 0, stream>>>(p_impp, p_imp);
    k_topk<<<4, 256, 0, stream>>>(p_imp, p_idx);
    // 10. out_cmp projection
    gemm(p_oc, proj_cmp_w, proj_cmp_b, p_ocp, 16384, 256, 256, 0);
    // 11. qkv_slc (reuse QKV)
    gemm(p_xs, qkv_slc_w, qkv_slc_b, p_qkv, 16384, 256, 768, 0);
    // 12-14. window branch
    k_xw<<<19600, 256, 0, stream>>>(p_xs, p_xw);
    gemm(p_xw, win_qkv_w, win_qkv_b, p_big, 19600, 256, 768, 0);
    k_attn_win<<<dim3(400,4), 64, 0, stream>>>(p_big, win_btab, p_xw);   // xw := owin_tok
    gemm(p_xw, win_proj_w, win_proj_b, p_owp, 19600, 256, 256, 0);
    // 15-17. selected branch
    k_gather_sel<<<1024, 256, 0, stream>>>(p_qkv, p_idx, p_ks, p_vs);
    k_attn_slc<<<dim3(64,4,4), 64, 0, stream>>>(p_qkv, p_ks, p_vs, p_oc);  // reuse OC
    gemm(p_oc, proj_slc_w, proj_slc_b, p_xw, 16384, 256, 256, 0);          // reuse XW = out_slc
    // 18-19. gate
    gemm(p_xs, gate_w1, gate_b1, p_hid, 16384, 256, 64, 1);
    gemm(p_hid, gate_w2, gate_b2, p_g, 16384, 64, 3, 2);
    // 20. combine -> (B,C,H,W) f32
    k_combine<<<dim3(128,8,4), dim3(32,8), 0, stream>>>(p_ocp, p_xw, p_owp, p_g,
                                                        (float*)d_out);
}

// Round 3
// 3180.577 us; speedup vs baseline: 1.0652x; 1.0652x over previous
//
#include <hip/hip_runtime.h>
#include <stdint.h>
#include <stddef.h>

// SpatialNSA on MI355X — round 3:
//  * attn_cmp/slc: uniform-address K/V reads (no LDS broadcast bottleneck),
//    2-wave key-split + LDS merge, 2-pass (importance needs final softmax).
//  * bf16 MFMA GEMM (16x16x32) for selection-SAFE gemms; weights pre-transposed
//    to [N][K] bf16. Selection-critical path (qkv_cmp, cmpk MLP) stays f32 so
//    top-k indices are bit-identical to the passing round-2 run.

#define DEV __device__ __forceinline__

typedef __attribute__((ext_vector_type(8))) short short8;
typedef __attribute__((ext_vector_type(4))) float f32x4;

DEV unsigned short f2bf(float f){
    unsigned u = __float_as_uint(f);
    u += 0x7FFFu + ((u>>16)&1u);   // RNE
    return (unsigned short)(u>>16);
}

// ---------------- transpose: x (B,C,N) f32 -> xs (B,N,C) f32 -------------
__global__ void k_xs(const float* __restrict__ x, float* __restrict__ xs){
    __shared__ float t[32][33];
    int b = blockIdx.z; int c0 = blockIdx.y*32; int n0 = blockIdx.x*32;
    int tx = threadIdx.x, ty = threadIdx.y;            // (32,8)
    for(int i=ty;i<32;i+=8)
        t[i][tx] = x[((size_t)(b*256 + c0+i))*4096 + n0 + tx];
    __syncthreads();
    for(int i=ty;i<32;i+=8)
        xs[((size_t)(b*4096 + n0+i))*256 + c0 + tx] = t[tx][i];
}

// -------- weight transpose+cast: W (K,N) f32 -> WT (N,K) bf16 ---------------
__global__ void k_wt(const float* __restrict__ W, unsigned short* __restrict__ WT,
                     int K, int N){
    __shared__ float t[32][33];
    int k0 = blockIdx.x*32, n0 = blockIdx.y*32;
    int tx = threadIdx.x, ty = threadIdx.y;            // (32,8)
    for(int i=ty;i<32;i+=8)
        if(k0+i<K && n0+tx<N) t[i][tx] = W[(size_t)(k0+i)*N + n0+tx];
    __syncthreads();
    for(int i=ty;i<32;i+=8)
        if(n0+i<N && k0+tx<K) WT[(size_t)(n0+i)*K + k0+tx] = f2bf(t[tx][i]);
}

// ---------------- f32 GEMM (selection-critical path) -------------------------
__global__ __launch_bounds__(256) void k_gemm(
        const float* __restrict__ A, const float* __restrict__ W,
        const float* __restrict__ bias, float* __restrict__ C,
        int M, int K, int Nn, int act)
{
    __shared__ float As[16][68];
    __shared__ float Bs[16][64];
    const int m0 = blockIdx.y*64, n0 = blockIdx.x*64;
    const int t = threadIdx.x, tx = t&15, ty = t>>4;
    float acc[4][4] = {};
    const int am = t>>2;
    const int ak = (t&3)*4;
    const bool arow_ok = (m0+am) < M;

    for(int k0=0;k0<K;k0+=16){
        float4 av = make_float4(0.f,0.f,0.f,0.f);
        if(arow_ok) av = *reinterpret_cast<const float4*>(&A[(size_t)(m0+am)*K + k0 + ak]);
        As[ak+0][am]=av.x; As[ak+1][am]=av.y; As[ak+2][am]=av.z; As[ak+3][am]=av.w;
        if((Nn & 3) == 0){
            int bn = (t&15)*4, bk = t>>4;
            float4 bv = make_float4(0.f,0.f,0.f,0.f);
            if(n0+bn < Nn)
                bv = *reinterpret_cast<const float4*>(&W[(size_t)(k0+bk)*Nn + n0+bn]);
            Bs[bk][bn]=bv.x; Bs[bk][bn+1]=bv.y; Bs[bk][bn+2]=bv.z; Bs[bk][bn+3]=bv.w;
        } else {
            int n = t&63, kb = t>>6;
            #pragma unroll
            for(int r=0;r<4;r++){
                int kk = r*4 + kb; float v = 0.f;
                if(n0+n < Nn) v = W[(size_t)(k0+kk)*Nn + n0+n];
                Bs[kk][n] = v;
            }
        }
        __syncthreads();
        #pragma unroll
        for(int kk=0;kk<16;kk++){
            float a0=As[kk][ty*4+0], a1=As[kk][ty*4+1], a2=As[kk][ty*4+2], a3=As[kk][ty*4+3];
            float b0=Bs[kk][tx*4+0], b1=Bs[kk][tx*4+1], b2=Bs[kk][tx*4+2], b3=Bs[kk][tx*4+3];
            acc[0][0]=fmaf(a0,b0,acc[0][0]); acc[0][1]=fmaf(a0,b1,acc[0][1]);
            acc[0][2]=fmaf(a0,b2,acc[0][2]); acc[0][3]=fmaf(a0,b3,acc[0][3]);
            acc[1][0]=fmaf(a1,b0,acc[1][0]); acc[1][1]=fmaf(a1,b1,acc[1][1]);
            acc[1][2]=fmaf(a1,b2,acc[1][2]); acc[1][3]=fmaf(a1,b3,acc[1][3]);
            acc[2][0]=fmaf(a2,b0,acc[2][0]); acc[2][1]=fmaf(a2,b1,acc[2][1]);
            acc[2][2]=fmaf(a2,b2,acc[2][2]); acc[2][3]=fmaf(a2,b3,acc[2][3]);
            acc[3][0]=fmaf(a3,b0,acc[3][0]); acc[3][1]=fmaf(a3,b1,acc[3][1]);
            acc[3][2]=fmaf(a3,b2,acc[3][2]); acc[3][3]=fmaf(a3,b3,acc[3][3]);
        }
        __syncthreads();
    }
    #pragma unroll
    for(int i=0;i<4;i++){
        int m = m0 + ty*4 + i;
        if(m >= M) continue;
        #pragma unroll
        for(int j=0;j<4;j++){
            int n = n0 + tx*4 + j;
            if(n >= Nn) continue;
            float v = acc[i][j] + bias[n];
            if(act==1)      v = 0.5f*v*(1.0f + erff(v*0.70710678118654752f));
            else if(act==2) v = 1.0f/(1.0f + expf(-v));
            C[(size_t)m*Nn + n] = v;
        }
    }
}

// ---------------- bf16 MFMA GEMM: C = act(A(M,K f32) @ W + bias) -------------
// WT is W transposed: [N][K] bf16. 128x128 tile, BK=64, 4 waves (2x2 of 64x64).
__global__ __launch_bounds__(256) void k_gemm_mfma(
        const float* __restrict__ A, const unsigned short* __restrict__ WT,
        const float* __restrict__ bias, float* __restrict__ C,
        int M, int K, int Nn, int act)
{
    __shared__ unsigned short Al[128*64];
    __shared__ unsigned short Bl[128*64];
    const int m0 = blockIdx.y*128, n0 = blockIdx.x*128;
    const int tid = threadIdx.x, lane = tid&63, wv = tid>>6;
    const int wm = (wv>>1)*64, wn = (wv&1)*64;
    f32x4 acc[4][4] = {};

    const int srow = tid>>1;           // 0..127
    const int sks  = (tid&1)*32;       // k element offset within tile

    for(int kt=0; kt<K; kt+=64){
        // stage A (f32 -> bf16, swizzled)
        {
            const bool ok = (m0+srow) < M;
            const float* src = &A[(size_t)(m0+srow)*K + kt + sks];
            #pragma unroll
            for(int c=0;c<4;c++){
                float4 v0 = make_float4(0,0,0,0), v1 = v0;
                if(ok){
                    v0 = *reinterpret_cast<const float4*>(src + c*8);
                    v1 = *reinterpret_cast<const float4*>(src + c*8 + 4);
                }
                short8 s;
                s[0]=(short)f2bf(v0.x); s[1]=(short)f2bf(v0.y);
                s[2]=(short)f2bf(v0.z); s[3]=(short)f2bf(v0.w);
                s[4]=(short)f2bf(v1.x); s[5]=(short)f2bf(v1.y);
                s[6]=(short)f2bf(v1.z); s[7]=(short)f2bf(v1.w);
                int byteoff = srow*128 + ((sks*2 + c*16) ^ ((srow&7)<<4));
                *reinterpret_cast<short8*>(reinterpret_cast<char*>(Al) + byteoff) = s;
            }
        }
        // stage B (bf16 -> bf16, swizzled)
        {
            const bool ok = (n0+srow) < Nn;
            const unsigned short* src = &WT[(size_t)(n0+srow)*K + kt + sks];
            #pragma unroll
            for(int c=0;c<4;c++){
                short8 s = {};
                if(ok) s = *reinterpret_cast<const short8*>(src + c*8);
                int byteoff = srow*128 + ((sks*2 + c*16) ^ ((srow&7)<<4));
                *reinterpret_cast<short8*>(reinterpret_cast<char*>(Bl) + byteoff) = s;
            }
        }
        __syncthreads();
        #pragma unroll
        for(int kb=0;kb<2;kb++){
            short8 af[4], bfr[4];
            #pragma unroll
            for(int i=0;i<4;i++){
                int ar = wm + i*16 + (lane&15);
                int abyte = ar*128 + (((kb*64) + ((lane>>4)*16)) ^ ((ar&7)<<4));
                af[i] = *reinterpret_cast<const short8*>(reinterpret_cast<const char*>(Al) + abyte);
                int br = wn + i*16 + (lane&15);
                int bbyte = br*128 + (((kb*64) + ((lane>>4)*16)) ^ ((br&7)<<4));
                bfr[i] = *reinterpret_cast<const short8*>(reinterpret_cast<const char*>(Bl) + bbyte);
            }
            #pragma unroll
            for(int mi=0;mi<4;mi++)
                #pragma unroll
                for(int ni=0;ni<4;ni++)
                    acc[mi][ni] = __builtin_amdgcn_mfma_f32_16x16x32_bf16(
                                      af[mi], bfr[ni], acc[mi][ni], 0, 0, 0);
        }
        __syncthreads();
    }
    // epilogue: C/D layout col=lane&15, row=(lane>>4)*4+r
    #pragma unroll
    for(int mi=0;mi<4;mi++){
        #pragma unroll
        for(int ni=0;ni<4;ni++){
            int col = n0 + wn + ni*16 + (lane&15);
            if(col >= Nn) continue;
            int rowb = m0 + wm + mi*16 + ((lane>>4)*4);
            float bv = bias[col];
            #pragma unroll
            for(int r=0;r<4;r++){
                int m = rowb + r;
                if(m >= M) continue;
                float v = acc[mi][ni][r] + bv;
                if(act==1)      v = 0.5f*v*(1.0f + erff(v*0.70710678118654752f));
                else if(act==2) v = 1.0f/(1.0f + expf(-v));
                C[(size_t)m*Nn + col] = v;
            }
        }
    }
}

// ------------- unfold (CBS=4, stride 2) with torch-quirk flat order -----------
__global__ void k_unfold(const float* __restrict__ qkv, const float* __restrict__ pos,
                         float* __restrict__ outA, int chanBase){
    int row = blockIdx.x;                 // 0..3843
    int b = row / 961, blk = row % 961;
    int bi = blk / 31, bj = blk % 31;
    for(int j = threadIdx.x; j < 4096; j += 256){
        int ch = j >> 4;
        int kh = (j >> 2) & 3, kw = j & 3;
        int n = (bi*2 + kh)*64 + (bj*2 + kw);
        float v = qkv[((size_t)(b*4096) + n)*768 + chanBase + ch];
        if(pos) v += pos[j];
        outA[(size_t)row*4096 + j] = v;
    }
}

// ------------- attention (cmp & slc): uniform K/V reads, 2-wave key-split -----
// qsrc rows: (b*4096+q)*768 + h*64 ; Km/Vm rows: (b*NK+key)*256 + h*64
__global__ __launch_bounds__(128) void k_attn2(
    const float* __restrict__ qsrc, const float* __restrict__ Km,
    const float* __restrict__ Vm, int NK,
    float* __restrict__ outp, float* __restrict__ impp)
{
    const int qt = blockIdx.x, h = blockIdx.y, b = blockIdx.z;
    const int lane = threadIdx.x & 63, wv = threadIdx.x >> 6;
    const int q = qt*64 + lane;

    const float4* qp = reinterpret_cast<const float4*>(
                           &qsrc[((size_t)(b*4096 + q))*768 + h*64]);
    float4 qv[16];
    #pragma unroll
    for(int i=0;i<16;++i) qv[i] = qp[i];

    const int half = (NK+1)>>1;
    const int k0 = wv ? half : 0;
    const int k1 = wv ? NK : half;

    const float4* kbase = reinterpret_cast<const float4*>(Km + ((size_t)b*NK)*256 + h*64);
    const float4* vbase = reinterpret_cast<const float4*>(Vm + ((size_t)b*NK)*256 + h*64);

    // pass 1: running max & denom over this wave's keys
    float m = -1e30f, l = 0.f;
    for(int key=k0; key<k1; ++key){
        const float4* kp = kbase + (size_t)key*64;
        float s0=0,s1=0,s2=0,s3=0;
        #pragma unroll
        for(int i=0;i<16;++i){
            float4 kv = kp[i];
            s0 = fmaf(qv[i].x, kv.x, s0);
            s1 = fmaf(qv[i].y, kv.y, s1);
            s2 = fmaf(qv[i].z, kv.z, s2);
            s3 = fmaf(qv[i].w, kv.w, s3);
        }
        float s = ((s0+s1)+(s2+s3)) * 0.125f;
        float mn = fmaxf(m, s);
        l = l*__expf(m - mn) + __expf(s - mn);
        m = mn;
    }

    // merge (m,l) across the two waves
    __shared__ float sm[2][64];
    __shared__ float sl[2][64];
    __shared__ float4 sacc[16][64];
    sm[wv][lane] = m; sl[wv][lane] = l;
    __syncthreads();
    float mo = sm[wv^1][lane], lo = sl[wv^1][lane];
    float mg = fmaxf(m, mo);
    float lg = l*__expf(m - mg) + lo*__expf(mo - mg);
    const float inv_l = 1.f / lg;

    // pass 2: probs, PV accumulate, importance
    float4 a4[16] = {};
    const int wgrow = (b*4 + h)*64 + qt;
    for(int key=k0; key<k1; ++key){
        const float4* kp = kbase + (size_t)key*64;
        float s0=0,s1=0,s2=0,s3=0;
        #pragma unroll
        for(int i=0;i<16;++i){
            float4 kv = kp[i];
            s0 = fmaf(qv[i].x, kv.x, s0);
            s1 = fmaf(qv[i].y, kv.y, s1);
            s2 = fmaf(qv[i].z, kv.z, s2);
            s3 = fmaf(qv[i].w, kv.w, s3);
        }
        float p = __expf(((s0+s1)+(s2+s3))*0.125f - mg);
        const float4* vp = vbase + (size_t)key*64;
        #pragma unroll
        for(int i=0;i<16;++i){
            float4 vv = vp[i];
            a4[i].x = fmaf(p, vv.x, a4[i].x);
            a4[i].y = fmaf(p, vv.y, a4[i].y);
            a4[i].z = fmaf(p, vv.z, a4[i].z);
            a4[i].w = fmaf(p, vv.w, a4[i].w);
        }
        if(impp){
            float pn = p * inv_l;
            #pragma unroll
            for(int off=32; off>0; off>>=1) pn += __shfl_xor(pn, off);
            if(lane==0) impp[(size_t)wgrow*961 + key] = pn;
        }
    }

    // merge accumulators, write normalized output (wave 0)
    if(wv==1){
        #pragma unroll
        for(int i=0;i<16;++i) sacc[i][lane] = a4[i];
    }
    __syncthreads();
    if(wv==0){
        float4* op4 = reinterpret_cast<float4*>(&outp[((size_t)(b*4096 + q))*256 + h*64]);
        #pragma unroll
        for(int i=0;i<16;++i){
            float4 o = sacc[i][lane];
            o.x = (a4[i].x + o.x)*inv_l;
            o.y = (a4[i].y + o.y)*inv_l;
            o.z = (a4[i].z + o.z)*inv_l;
            o.w = (a4[i].w + o.w)*inv_l;
            op4[i] = o;
        }
    }
}

// ------------- deterministic importance reduce ------------
__global__ void k_imp_reduce(const float* __restrict__ impp, float* __restrict__ imp){
    int blk = blockIdx.x*256 + threadIdx.x;
    int b = blockIdx.y;
    if(blk >= 961) return;
    float s = 0.f;
    for(int r=0;r<256;r++) s += impp[(size_t)(b*256 + r)*961 + blk];
    imp[b*961 + blk] = s;
}

// ------------- top-16 with lowest-index tie-break ----------------------------
__global__ void k_topk(const float* __restrict__ imp, int* __restrict__ idx){
    int b = blockIdx.x;
    __shared__ float v[961];
    __shared__ float bestv[256];
    __shared__ int   besti[256];
    int t = threadIdx.x;
    for(int i=t;i<961;i+=256) v[i] = imp[b*961+i];
    __syncthreads();
    for(int it=0; it<16; it++){
        float bv = -1e30f; int bi = 0;
        for(int i=t;i<961;i+=256){
            if(v[i] > bv){ bv=v[i]; bi=i; }
        }
        bestv[t]=bv; besti[t]=bi;
        __syncthreads();
        if(t==0){
            float gb=-1e30f; int gi=0;
            for(int i=0;i<256;i++){
                if(bestv[i]>gb || (bestv[i]==gb && besti[i]<gi)){ gb=bestv[i]; gi=besti[i]; }
            }
            idx[b*16+it] = gi;
            v[gi] = -1e30f;
        }
        __syncthreads();
    }
}

// ------------- gather selected K/V (quirk layout, clip to 255) ----------------
__global__ void k_gather_sel(const float* __restrict__ qkv2, const int* __restrict__ idx,
                             float* __restrict__ Ks, float* __restrict__ Vs){
    int row = blockIdx.x;            // b*256 + t ; t = sel*16 + p
    int b = row >> 8, tt = row & 255;
    int sel = tt >> 4, p = tt & 15;
    int blk = idx[b*16+sel]; if(blk > 255) blk = 255;
    int bi = blk >> 4, bj = blk & 15;
    int cc = threadIdx.x;
    int y = bi*4 + ((cc>>2)&3), xx = bj*4 + (cc&3);
    int ch = p*16 + (cc>>4);
    size_t src = ((size_t)(b*4096) + y*64 + xx)*768;
    Ks[(size_t)row*256 + cc] = qkv2[src + 256 + ch];
    Vs[(size_t)row*256 + cc] = qkv2[src + 512 + ch];
}

// ------------- build padded window tokens xw (400*49, 256) -------------------
__global__ void k_xw(const float* __restrict__ xs, float* __restrict__ xw){
    int row = blockIdx.x;             // wb*49 + t
    int wb = row / 49, t = row % 49;
    int b = wb / 100, wrem = wb % 100;
    int wy = wrem / 10, wx = wrem % 10;
    int ty = t / 7, tx = t % 7;
    int y = wy*7 + ty, xx = wx*7 + tx;
    int c = threadIdx.x;
    float v = 0.f;
    if(y < 64 && xx < 64) v = xs[((size_t)(b*4096) + y*64 + xx)*256 + c];
    xw[(size_t)row*256 + c] = v;
}

// ------------- window attention: 49 tokens, rel-pos bias ---------------------
__global__ __launch_bounds__(64) void k_attn_win(
    const float* __restrict__ qkvw, const float* __restrict__ btab,
    float* __restrict__ outp)
{
    const int wb = blockIdx.x, h = blockIdx.y;
    const int lane = threadIdx.x;
    __shared__ float lk[49][64];
    __shared__ float lv[49][64];
    __shared__ float ls[49][51];
    __shared__ float lbias[169];
    for(int i=lane;i<169;i+=64) lbias[i] = btab[i*4 + h];
    for(int r=0;r<49;r++){
        lk[r][lane] = qkvw[((size_t)(wb*49 + r))*768 + 256 + h*64 + lane];
        lv[r][lane] = qkvw[((size_t)(wb*49 + r))*768 + 512 + h*64 + lane];
    }
    __syncthreads();
    if(lane < 49){
        const float* qptr = &qkvw[((size_t)(wb*49 + lane))*768 + h*64];
        float qreg[64];
        #pragma unroll
        for(int d=0;d<64;++d) qreg[d] = qptr[d];
        int ih = lane/7, iw = lane%7;
        float m = -1e30f;
        for(int j=0;j<49;j++){
            float s0=0,s1=0,s2=0,s3=0;
            #pragma unroll
            for(int d=0; d<64; d+=4){
                s0 = fmaf(qreg[d+0], lk[j][d+0], s0);
                s1 = fmaf(qreg[d+1], lk[j][d+1], s1);
                s2 = fmaf(qreg[d+2], lk[j][d+2], s2);
                s3 = fmaf(qreg[d+3], lk[j][d+3], s3);
            }
            int jh=j/7, jw=j%7;
            float s = ((s0+s1)+(s2+s3))*0.125f + lbias[(ih-jh+6)*13 + (iw-jw+6)];
            ls[lane][j] = s;
            m = fmaxf(m, s);
        }
        float l = 0.f;
        for(int j=0;j<49;j++){ float p = __expf(ls[lane][j] - m); ls[lane][j] = p; l += p; }
        float inv = 1.f/l;
        float* op = &outp[((size_t)(wb*49 + lane))*256 + h*64];
        for(int d=0;d<64;d++){
            float a0=0,a1=0;
            for(int j=0;j<48;j+=2){
                a0 = fmaf(ls[lane][j],   lv[j][d],   a0);
                a1 = fmaf(ls[lane][j+1], lv[j+1][d], a1);
            }
            a0 = fmaf(ls[lane][48], lv[48][d], a0);
            op[d] = (a0+a1)*inv;
        }
    }
}

// ------------- final gated combine + transpose to (B,C,H,W) f32 -------------
__global__ void k_combine(const float* __restrict__ ocp, const float* __restrict__ osp,
                          const float* __restrict__ owp, const float* __restrict__ g,
                          float* __restrict__ out){
    __shared__ float tile[32][33];
    int b = blockIdx.z; int c0 = blockIdx.y*32, n0 = blockIdx.x*32;
    int tx = threadIdx.x, ty = threadIdx.y;    // (32,8)
    for(int i=ty;i<32;i+=8){
        int n = n0 + i;
        float g0 = g[(size_t)(b*4096+n)*3 + 0];
        float g1 = g[(size_t)(b*4096+n)*3 + 1];
        float g2 = g[(size_t)(b*4096+n)*3 + 2];
        int y = n >> 6, xx = n & 63;
        int wy = y/7, ty2 = y%7, wx = xx/7, tx2 = xx%7;
        size_t wrow = (size_t)(b*100 + wy*10 + wx)*49 + ty2*7 + tx2;
        size_t base = ((size_t)(b*4096) + n)*256 + c0;
        float vc = ocp[base + tx];
        float vs = osp[base + tx];
        float vw = owp[wrow*256 + c0 + tx];
        tile[i][tx] = g0*vc + g1*vs + g2*vw;
    }
    __syncthreads();
    for(int i=ty;i<32;i+=8)
        out[((size_t)(b*256 + c0+i))*4096 + n0 + tx] = tile[tx][i];
}

// =============================== host side ===================================
extern "C" void kernel_launch(void* const* d_in, const int* in_sizes, int n_in,
                              void* d_out, int out_size, void* d_ws, size_t ws_size,
                              hipStream_t stream)
{
    typedef const float* fp;
    fp x          = (fp)d_in[0];
    fp qkv_cmp_w  = (fp)d_in[1];  fp qkv_cmp_b = (fp)d_in[2];
    fp qkv_slc_w  = (fp)d_in[3];  fp qkv_slc_b = (fp)d_in[4];
    fp cmpk_w1    = (fp)d_in[5];  fp cmpk_b1   = (fp)d_in[6];
    fp cmpk_w2    = (fp)d_in[7];  fp cmpk_b2   = (fp)d_in[8];
    fp cmpv_w1    = (fp)d_in[9];  fp cmpv_b1   = (fp)d_in[10];
    fp cmpv_w2    = (fp)d_in[11]; fp cmpv_b2   = (fp)d_in[12];
    fp pos_embed  = (fp)d_in[13];
    fp win_qkv_w  = (fp)d_in[14]; fp win_qkv_b = (fp)d_in[15];
    fp win_proj_w = (fp)d_in[16]; fp win_proj_b= (fp)d_in[17];
    fp win_btab   = (fp)d_in[18];
    fp proj_cmp_w = (fp)d_in[19]; fp proj_cmp_b= (fp)d_in[20];
    fp proj_slc_w = (fp)d_in[21]; fp proj_slc_b= (fp)d_in[22];
    fp gate_w1    = (fp)d_in[23]; fp gate_b1   = (fp)d_in[24];
    fp gate_w2    = (fp)d_in[25]; fp gate_b2   = (fp)d_in[26];
    (void)in_sizes; (void)n_in; (void)out_size;

    char* ws = (char*)d_ws;
    size_t off = 0;
    auto alloc = [&](size_t bytes)->size_t{
        size_t r = off; off += (bytes + 255) & ~(size_t)255; return r;
    };
    const size_t XS   = alloc((size_t)16384*256*4);
    const size_t QKV  = alloc((size_t)16384*768*4);
    const size_t BIGA = alloc((size_t)3844*4096*4);
    const size_t HID  = alloc((size_t)3844*512*4);
    const size_t KC   = alloc((size_t)3844*256*4);
    const size_t VC   = alloc((size_t)3844*256*4);
    const size_t OC   = alloc((size_t)16384*256*4);
    const size_t IMPP = alloc((size_t)1024*961*4);
    const size_t IMP  = alloc((size_t)4*961*4);
    const size_t IDX  = alloc((size_t)4*16*4);
    const size_t OCP  = alloc((size_t)16384*256*4);
    const size_t XW   = alloc((size_t)19600*256*4);
    const size_t OWP  = alloc((size_t)19600*256*4);
    const size_t KS   = alloc((size_t)4*256*256*4);
    const size_t VS   = alloc((size_t)4*256*256*4);
    const size_t G2   = alloc((size_t)16384*3*4);
    // bf16 transposed weights [N][K]
    const size_t TQS  = alloc((size_t)768*256*2);   // qkv_slc
    const size_t TWQ  = alloc((size_t)768*256*2);   // win_qkv
    const size_t TV1  = alloc((size_t)512*4096*2);  // cmpv_w1
    const size_t TV2  = alloc((size_t)256*512*2);   // cmpv_w2
    const size_t TPC  = alloc((size_t)256*256*2);   // proj_cmp
    const size_t TPS  = alloc((size_t)256*256*2);   // proj_slc
    const size_t TWP  = alloc((size_t)256*256*2);   // win_proj
    const size_t TG1  = alloc((size_t)64*256*2);    // gate_w1
    if(off > ws_size) return;

    float* p_xs  = (float*)(ws + XS);
    float* p_qkv = (float*)(ws + QKV);
    float* p_big = (float*)(ws + BIGA);
    float* p_hid = (float*)(ws + HID);
    float* p_kc  = (float*)(ws + KC);
    float* p_vc  = (float*)(ws + VC);
    float* p_oc  = (float*)(ws + OC);
    float* p_impp= (float*)(ws + IMPP);
    float* p_imp = (float*)(ws + IMP);
    int*   p_idx = (int*)  (ws + IDX);
    float* p_ocp = (float*)(ws + OCP);
    float* p_xw  = (float*)(ws + XW);
    float* p_owp = (float*)(ws + OWP);
    float* p_ks  = (float*)(ws + KS);
    float* p_vs  = (float*)(ws + VS);
    float* p_g   = (float*)(ws + G2);
    unsigned short* t_qs = (unsigned short*)(ws + TQS);
    unsigned short* t_wq = (unsigned short*)(ws + TWQ);
    unsigned short* t_v1 = (unsigned short*)(ws + TV1);
    unsigned short* t_v2 = (unsigned short*)(ws + TV2);
    unsigned short* t_pc = (unsigned short*)(ws + TPC);
    unsigned short* t_ps = (unsigned short*)(ws + TPS);
    unsigned short* t_wp = (unsigned short*)(ws + TWP);
    unsigned short* t_g1 = (unsigned short*)(ws + TG1);

    auto gemm = [&](const float* A, fp W, fp bias, float* Cc, int M, int K, int Nn, int act){
        dim3 g((Nn+63)/64, (M+63)/64);
        k_gemm<<<g, 256, 0, stream>>>(A, W, bias, Cc, M, K, Nn, act);
    };
    auto wt = [&](fp W, unsigned short* WT, int K, int Nn){
        k_wt<<<dim3(K/32, Nn/32), dim3(32,8), 0, stream>>>(W, WT, K, Nn);
    };
    auto mgemm = [&](const float* A, const unsigned short* WT, fp bias, float* Cc,
                     int M, int K, int Nn, int act){
        dim3 g((Nn+127)/128, (M+127)/128);
        k_gemm_mfma<<<g, 256, 0, stream>>>(A, WT, bias, Cc, M, K, Nn, act);
    };

    // 0. transposed bf16 weights (selection-safe gemms)
    wt(qkv_slc_w, t_qs, 256, 768);
    wt(win_qkv_w, t_wq, 256, 768);
    wt(cmpv_w1,   t_v1, 4096, 512);
    wt(cmpv_w2,   t_v2, 512, 256);
    wt(proj_cmp_w,t_pc, 256, 256);
    wt(proj_slc_w,t_ps, 256, 256);
    wt(win_proj_w,t_wp, 256, 256);
    wt(gate_w1,   t_g1, 256, 64);

    // 1. xs = transpose(x)
    k_xs<<<dim3(128,8,4), dim3(32,8), 0, stream>>>(x, p_xs);
    // 2. qkv_cmp (f32 — selection-critical)
    gemm(p_xs, qkv_cmp_w, qkv_cmp_b, p_qkv, 16384, 256, 768, 0);
    // 3-5. compressed K path (f32 — selection-critical)
    k_unfold<<<3844, 256, 0, stream>>>(p_qkv, pos_embed, p_big, 256);
    gemm(p_big, cmpk_w1, cmpk_b1, p_hid, 3844, 4096, 512, 1);
    gemm(p_hid, cmpk_w2, cmpk_b2, p_kc, 3844, 512, 256, 0);
    // 6-8. compressed V path (MFMA)
    k_unfold<<<3844, 256, 0, stream>>>(p_qkv, nullptr, p_big, 512);
    mgemm(p_big, t_v1, cmpv_b1, p_hid, 3844, 4096, 512, 1);
    mgemm(p_hid, t_v2, cmpv_b2, p_vc, 3844, 512, 256, 0);
    // 9. compressed attention + importance
    k_attn2<<<dim3(64,4,4), 128, 0, stream>>>(p_qkv, p_kc, p_vc, 961, p_oc, p_impp);
    k_imp_reduce<<<dim3(4,4), 256, 0, stream>>>(p_impp, p_imp);
    k_topk<<<4, 256, 0, stream>>>(p_imp, p_idx);
    // 10. out_cmp projection (MFMA)
    mgemm(p_oc, t_pc, proj_cmp_b, p_ocp, 16384, 256, 256, 0);
    // 11. qkv_slc (MFMA)
    mgemm(p_xs, t_qs, qkv_slc_b, p_qkv, 16384, 256, 768, 0);
    // 12-14. window branch
    k_xw<<<19600, 256, 0, stream>>>(p_xs, p_xw);
    mgemm(p_xw, t_wq, win_qkv_b, p_big, 19600, 256, 768, 0);
    k_attn_win<<<dim3(400,4), 64, 0, stream>>>(p_big, win_btab, p_xw);   // xw := owin_tok
    mgemm(p_xw, t_wp, win_proj_b, p_owp, 19600, 256, 256, 0);
    // 15-17. selected branch
    k_gather_sel<<<1024, 256, 0, stream>>>(p_qkv, p_idx, p_ks, p_vs);
    k_attn2<<<dim3(64,4,4), 128, 0, stream>>>(p_qkv, p_ks, p_vs, 256, p_oc, nullptr);
    mgemm(p_oc, t_ps, proj_slc_b, p_xw, 16384, 256, 256, 0);             // xw := out_slc
    // 18-19. gate
    mgemm(p_xs, t_g1, gate_b1, p_hid, 16384, 256, 64, 1);
    gemm(p_hid, gate_w2, gate_b2, p_g, 16384, 64, 3, 2);
    // 20. combine
    k_combine<<<dim3(128,8,4), dim3(32,8), 0, stream>>>(p_ocp, p_xw, p_owp, p_g,
                                                        (float*)d_out);
}